// Round 5
// baseline (352.105 us; speedup 1.0000x reference)
//
#include <hip/hip_runtime.h>
#include <stdint.h>

typedef __bf16 bf16;
typedef float f32x4 __attribute__((ext_vector_type(4)));
typedef bf16 bf16x8 __attribute__((ext_vector_type(8)));
typedef bf16 bf16x4 __attribute__((ext_vector_type(4)));

#define MFMA16(a, b, c) __builtin_amdgcn_mfma_f32_16x16x32_bf16((a), (b), (c), 0, 0, 0)
#define EXP2F(x) __builtin_amdgcn_exp2f(x)

__device__ __forceinline__ void gll16(const void* g, void* l) {
  __builtin_amdgcn_global_load_lds((const __attribute__((address_space(1))) void*)g,
                                   (__attribute__((address_space(3))) void*)l, 16, 0, 0);
}

// ---------------------------------------------------------------------------
// fp32 -> bf16 conversion of all tensors, one launch.
// ---------------------------------------------------------------------------
__global__ __launch_bounds__(256) void convert_all(
    const float4* __restrict__ Q, const float4* __restrict__ K, const float4* __restrict__ V,
    const float4* __restrict__ Wq, const float4* __restrict__ Wk, const float4* __restrict__ Wv,
    const float4* __restrict__ fcw, const float4* __restrict__ E,
    bf16x4* __restrict__ Xq, bf16x4* __restrict__ Xk, bf16x4* __restrict__ Xv,
    bf16x4* __restrict__ Wqb, bf16x4* __restrict__ Wkb, bf16x4* __restrict__ Wvb,
    bf16x4* __restrict__ fcb, bf16x4* __restrict__ Eb) {
  int i = blockIdx.x * 256 + threadIdx.x;
  const float4* s;
  bf16x4* d;
  int off;
  if (i < 1048576) { s = Q; d = Xq; off = i; }
  else if (i < 2097152) { s = K; d = Xk; off = i - 1048576; }
  else if (i < 3145728) { s = V; d = Xv; off = i - 2097152; }
  else if (i < 3211264) { s = Wq; d = Wqb; off = i - 3145728; }
  else if (i < 3276800) { s = Wk; d = Wkb; off = i - 3211264; }
  else if (i < 3342336) { s = Wv; d = Wvb; off = i - 3276800; }
  else if (i < 3407872) { s = fcw; d = fcb; off = i - 3342336; }
  else { s = E; d = Eb; off = i - 3407872; }
  float4 v = s[off];
  bf16x4 o;
  o[0] = (bf16)v.x; o[1] = (bf16)v.y; o[2] = (bf16)v.z; o[3] = (bf16)v.w;
  d[off] = o;
}

// ---------------------------------------------------------------------------
// GEMM core: C[128x128] = A[128x512] * Bt[128x512]^T (row-major bf16).
// ---------------------------------------------------------------------------
__device__ __forceinline__ void gemm_core(const bf16* __restrict__ A, const bf16* __restrict__ Bt,
                                          bf16* ldsA, bf16* ldsB, int m0, int n0,
                                          f32x4 acc[4][4]) {
  const int t = threadIdx.x;
  const int lane = t & 63, w = t >> 6;
  const int l15 = lane & 15, quad = lane >> 4;
  const int wm = w >> 1, wn = w & 1;
#pragma unroll
  for (int i = 0; i < 4; i++)
#pragma unroll
    for (int j = 0; j < 4; j++) acc[i][j] = (f32x4){0.f, 0.f, 0.f, 0.f};

  const int ch0 = t, ch1 = t + 256;
  const int r0 = ch0 >> 2, c0 = (ch0 & 3) ^ (r0 & 3);
  const int r1 = ch1 >> 2, c1 = (ch1 & 3) ^ (r1 & 3);

  int aoff[4], boff[4];
#pragma unroll
  for (int mt = 0; mt < 4; mt++) {
    int m = wm * 64 + mt * 16 + l15;
    aoff[mt] = (m << 6) + ((quad ^ (l15 & 3)) << 4);
    int n = wn * 64 + mt * 16 + l15;
    boff[mt] = (n << 6) + ((quad ^ (l15 & 3)) << 4);
  }
  bf16* ldsA1 = ldsA + w * 512;
  bf16* ldsA2 = ldsA + 2048 + w * 512;
  bf16* ldsB1 = ldsB + w * 512;
  bf16* ldsB2 = ldsB + 2048 + w * 512;

  for (int kt = 0; kt < 512; kt += 32) {
    gll16(A + (size_t)(m0 + r0) * 512 + kt + c0 * 8, ldsA1);
    gll16(A + (size_t)(m0 + r1) * 512 + kt + c1 * 8, ldsA2);
    gll16(Bt + (size_t)(n0 + r0) * 512 + kt + c0 * 8, ldsB1);
    gll16(Bt + (size_t)(n0 + r1) * 512 + kt + c1 * 8, ldsB2);
    __syncthreads();
    bf16x8 af[4], bfr[4];
#pragma unroll
    for (int mt = 0; mt < 4; mt++) af[mt] = *(const bf16x8*)((const char*)ldsA + aoff[mt]);
#pragma unroll
    for (int nt = 0; nt < 4; nt++) bfr[nt] = *(const bf16x8*)((const char*)ldsB + boff[nt]);
#pragma unroll
    for (int mt = 0; mt < 4; mt++)
#pragma unroll
      for (int nt = 0; nt < 4; nt++)
        acc[mt][nt] = MFMA16(af[mt], bfr[nt], acc[mt][nt]);
    __syncthreads();
  }
}

__global__ __launch_bounds__(256) void proj_gemm(
    const bf16* __restrict__ Xq, const bf16* __restrict__ Xk, const bf16* __restrict__ Xv,
    const bf16* __restrict__ Wq, const bf16* __restrict__ Wk, const bf16* __restrict__ Wv,
    const float* __restrict__ bq, const float* __restrict__ bk, const float* __restrict__ bv,
    bf16* __restrict__ qb, bf16* __restrict__ kb, bf16* __restrict__ vb) {
  __shared__ bf16 ldsA[128 * 32];
  __shared__ bf16 ldsB[128 * 32];
  const int z = blockIdx.z;
  const bf16* A = z == 0 ? Xq : (z == 1 ? Xk : Xv);
  const bf16* W = z == 0 ? Wq : (z == 1 ? Wk : Wv);
  const float* bias = z == 0 ? bq : (z == 1 ? bk : bv);
  bf16* out = z == 0 ? qb : (z == 1 ? kb : vb);
  const int m0 = blockIdx.x * 128, n0 = blockIdx.y * 128;
  f32x4 acc[4][4];
  gemm_core(A, W, ldsA, ldsB, m0, n0, acc);

  const int t = threadIdx.x;
  const int lane = t & 63, w = t >> 6;
  const int l15 = lane & 15, quad = lane >> 4;
  const int wm = w >> 1, wn = w & 1;
#pragma unroll
  for (int mt = 0; mt < 4; mt++)
#pragma unroll
    for (int nt = 0; nt < 4; nt++)
#pragma unroll
      for (int r = 0; r < 4; r++) {
        int gm = m0 + wm * 64 + mt * 16 + quad * 4 + r;
        int gn = n0 + wn * 64 + nt * 16 + l15;
        float v = acc[mt][nt][r] + bias[gn];
        int b = gm >> 11, l = gm & 2047, h = gn >> 6, d = gn & 63;
        out[(((size_t)(b * 8 + h)) * 2048 + l) * 64 + d] = (bf16)v;
      }
}

__global__ __launch_bounds__(256) void final_gemm(const bf16* __restrict__ A,
                                                  const bf16* __restrict__ W,
                                                  const float* __restrict__ bias,
                                                  float* __restrict__ out) {
  __shared__ bf16 ldsA[128 * 32];
  __shared__ bf16 ldsB[128 * 32];
  const int m0 = blockIdx.x * 128, n0 = blockIdx.y * 128;
  f32x4 acc[4][4];
  gemm_core(A, W, ldsA, ldsB, m0, n0, acc);

  const int t = threadIdx.x;
  const int lane = t & 63, w = t >> 6;
  const int l15 = lane & 15, quad = lane >> 4;
  const int wm = w >> 1, wn = w & 1;
#pragma unroll
  for (int mt = 0; mt < 4; mt++)
#pragma unroll
    for (int nt = 0; nt < 4; nt++)
#pragma unroll
      for (int r = 0; r < 4; r++) {
        int gm = m0 + wm * 64 + mt * 16 + quad * 4 + r;
        int gn = n0 + wn * 64 + nt * 16 + l15;
        out[(size_t)gm * 512 + gn] = acc[mt][nt][r] + bias[gn];
      }
}

// v (B,H,L,64) -> vT (B,H,64,L)
__global__ __launch_bounds__(256) void transpose_v(const bf16* __restrict__ vbuf,
                                                   bf16* __restrict__ vT) {
  __shared__ bf16 tile[64][72];
  const int bh = blockIdx.y, l0 = blockIdx.x * 64;
  const bf16* src = vbuf + ((size_t)bh * 2048 + l0) * 64;
  bf16* dst = vT + (size_t)bh * 64 * 2048 + l0;
  const int t = threadIdx.x;
#pragma unroll
  for (int p = 0; p < 2; p++) {
    int ch = t + p * 256;
    int r = ch >> 3, c8 = ch & 7;
    *(bf16x8*)&tile[r][c8 * 8] = *(const bf16x8*)&src[(size_t)r * 64 + c8 * 8];
  }
  __syncthreads();
#pragma unroll
  for (int p = 0; p < 2; p++) {
    int ch = t + p * 256;
    int dr = ch >> 3, lc = ch & 7;
    bf16x8 v;
#pragma unroll
    for (int j = 0; j < 8; j++) v[j] = tile[lc * 8 + j][dr];
    *(bf16x8*)&dst[(size_t)dr * 2048 + lc * 8] = v;
  }
}

// ---------------------------------------------------------------------------
// Flash attention + relative position, causal. Max-free unnormalized softmax.
// Wave = 16 q-rows; block = 4 waves = 64 rows; every wave in a block does the
// SAME t4+1 j-tiles (K/V/E B-frags direct from global -> L1-shared across the
// 4 lockstep waves; no LDS staging, ZERO barriers). Skew via transposed
// skew-store TskewT[j][u] (pitch 20 f32): 20 predicated scalar writes,
// 4x ds_read_b128 gives the f32x4 addend per S-tile. Grid 1024, phase-paired
// heavy/light blocks -> constant 66 tile-units per CU.
// ---------------------------------------------------------------------------
__global__ __launch_bounds__(256, 4) void attn_kernel(const bf16* __restrict__ qbuf,
                                                      const bf16* __restrict__ kbuf,
                                                      const bf16* __restrict__ vT,
                                                      const bf16* __restrict__ Eb,
                                                      bf16* __restrict__ attn) {
  __shared__ float Ts[4][64 * 20];  // per-wave skewed T^T: [j][u], pitch 20
  __shared__ bf16 Pl[4][16 * 72];   // per-wave P: [u][j], pitch 72
  const int t = threadIdx.x, w = t >> 6, lane = t & 63;
  const int l15 = lane & 15, quad = lane >> 4;
  const int x = blockIdx.x;
  const int pid = x & 511, phase = x >> 9;
  const int a = pid & 15, bh = pid >> 4;
  const int t4 = phase ? a : 31 - a;  // block strip; heavy strips in phase 0
  const int i0 = t4 * 64 + w * 16;    // this wave's 16 q-rows
  float* Tw = Ts[w];
  bf16* Pw = Pl[w];
  const bf16* qh = qbuf + (size_t)bh * 2048 * 64;
  const bf16* kh = kbuf + (size_t)bh * 2048 * 64;
  const bf16* vh = vT + (size_t)bh * 64 * 2048;

  bf16x8 aq0, aq1;
  {
    const bf16* qrow = qh + (size_t)(i0 + l15) * 64 + quad * 8;
    aq0 = *(const bf16x8*)qrow;
    aq1 = *(const bf16x8*)(qrow + 32);
  }
  bf16x8 ones;
#pragma unroll
  for (int j = 0; j < 8; j++) ones[j] = (bf16)1.0f;

  f32x4 O[4], Osum;
  Osum = (f32x4){0.f, 0.f, 0.f, 0.f};
#pragma unroll
  for (int i = 0; i < 4; i++) O[i] = (f32x4){0.f, 0.f, 0.f, 0.f};
  const float sc = 0.125f * 1.44269504088896f;  // 1/sqrt(64) * log2(e)

  for (int jt = 0; jt <= t4; jt++) {
    const int j0 = jt * 64;
    const int ebase = 2047 - i0 + j0 - 15;
    // ---- T band (16x80) via MFMA, written skew-transposed: TskewT[j][u] ----
#pragma unroll
    for (int nt = 0; nt < 5; nt++) {
      int er = ebase + nt * 16 + l15;
      er = er > 2047 ? 2047 : er;  // clamped rows feed only masked entries
      const bf16* erow = Eb + (size_t)er * 64 + quad * 8;
      bf16x8 b0 = *(const bf16x8*)erow;
      bf16x8 b1 = *(const bf16x8*)(erow + 32);
      f32x4 z = (f32x4){0.f, 0.f, 0.f, 0.f};
      z = MFMA16(aq0, b0, z);
      z = MFMA16(aq1, b1, z);
#pragma unroll
      for (int r = 0; r < 4; r++) {
        int uu = quad * 4 + r;
        int j = nt * 16 + l15 - 15 + uu;  // skewed column
        if (j >= 0 && j < 64) Tw[j * 20 + uu] = z[r];
      }
    }
    // ---- S = q @ k^T (16x64), B-frags direct from global ----
    f32x4 s[4];
#pragma unroll
    for (int nt = 0; nt < 4; nt++) {
      const bf16* krow = kh + (size_t)(j0 + nt * 16 + l15) * 64 + quad * 8;
      bf16x8 b0 = *(const bf16x8*)krow;
      bf16x8 b1 = *(const bf16x8*)(krow + 32);
      f32x4 z = (f32x4){0.f, 0.f, 0.f, 0.f};
      z = MFMA16(aq0, b0, z);
      z = MFMA16(aq1, b1, z);
      s[nt] = z;
    }
    // ---- skew add (b128 read) + scale + mask + exp2 + P write ----
#pragma unroll
    for (int nt = 0; nt < 4; nt++) {
      int j = nt * 16 + l15;
      f32x4 skew = *(const f32x4*)&Tw[j * 20 + quad * 4];
#pragma unroll
      for (int r = 0; r < 4; r++) {
        int uu = quad * 4 + r;
        float logit = (s[nt][r] + skew[r]) * sc;
        if (j0 + j > i0 + uu) logit = -1e30f;  // causal; exp2 -> 0
        Pw[uu * 72 + j] = (bf16)EXP2F(logit);
      }
    }
    // ---- PV: O += P @ V ; Osum += P @ ones ----
    bf16x8 pa0 = *(const bf16x8*)&Pw[l15 * 72 + quad * 8];
    bf16x8 pa1 = *(const bf16x8*)&Pw[l15 * 72 + 32 + quad * 8];
    Osum = MFMA16(pa0, ones, Osum);
    Osum = MFMA16(pa1, ones, Osum);
#pragma unroll
    for (int nt = 0; nt < 4; nt++) {
      const bf16* vrow = vh + (size_t)(nt * 16 + l15) * 2048 + j0 + quad * 8;
      bf16x8 b0 = *(const bf16x8*)vrow;
      bf16x8 b1 = *(const bf16x8*)(vrow + 32);
      O[nt] = MFMA16(pa0, b0, O[nt]);
      O[nt] = MFMA16(pa1, b1, O[nt]);
    }
  }
  // ---- epilogue: O / rowsum, write (B,L,H*DH) bf16 ----
  const int b = bh >> 3, hh = bh & 7;
  float inv[4];
#pragma unroll
  for (int r = 0; r < 4; r++) inv[r] = 1.0f / Osum[r];
  bf16* orow = attn + ((size_t)(b * 2048 + i0)) * 512 + hh * 64;
#pragma unroll
  for (int nt = 0; nt < 4; nt++)
#pragma unroll
    for (int r = 0; r < 4; r++)
      orow[(size_t)(quad * 4 + r) * 512 + nt * 16 + l15] = (bf16)(O[nt][r] * inv[r]);
}

// ---------------------------------------------------------------------------
extern "C" void kernel_launch(void* const* d_in, const int* in_sizes, int n_in,
                              void* d_out, int out_size, void* d_ws, size_t ws_size,
                              hipStream_t stream) {
  const float* Q = (const float*)d_in[0];
  const float* K = (const float*)d_in[1];
  const float* V = (const float*)d_in[2];
  const float* Wq = (const float*)d_in[4];
  const float* bq = (const float*)d_in[5];
  const float* Wk = (const float*)d_in[6];
  const float* bk = (const float*)d_in[7];
  const float* Wv = (const float*)d_in[8];
  const float* bv = (const float*)d_in[9];
  const float* fcw = (const float*)d_in[10];
  const float* fcb = (const float*)d_in[11];
  const float* E = (const float*)d_in[12];

  char* ws = (char*)d_ws;
  bf16* Xq = (bf16*)(ws + 0);
  bf16* Xk = (bf16*)(ws + 8388608);
  bf16* Xv = (bf16*)(ws + 16777216);
  bf16* Wqb = (bf16*)(ws + 25165824);
  bf16* Wkb = (bf16*)(ws + 25690112);
  bf16* Wvb = (bf16*)(ws + 26214400);
  bf16* fcwb = (bf16*)(ws + 26738688);
  bf16* Eb = (bf16*)(ws + 27262976);
  bf16* qbuf = (bf16*)(ws + 27525120);
  bf16* kbuf = (bf16*)(ws + 35913728);
  bf16* vbuf = (bf16*)(ws + 44302336);
  bf16* vTb = Xk;
  bf16* attnb = Xq;

  convert_all<<<13440, 256, 0, stream>>>(
      (const float4*)Q, (const float4*)K, (const float4*)V, (const float4*)Wq,
      (const float4*)Wk, (const float4*)Wv, (const float4*)fcw, (const float4*)E,
      (bf16x4*)Xq, (bf16x4*)Xk, (bf16x4*)Xv, (bf16x4*)Wqb, (bf16x4*)Wkb,
      (bf16x4*)Wvb, (bf16x4*)fcwb, (bf16x4*)Eb);

  proj_gemm<<<dim3(64, 4, 3), 256, 0, stream>>>(Xq, Xk, Xv, Wqb, Wkb, Wvb, bq, bk, bv,
                                                qbuf, kbuf, vbuf);

  transpose_v<<<dim3(32, 32), 256, 0, stream>>>(vbuf, vTb);

  attn_kernel<<<1024, 256, 0, stream>>>(qbuf, kbuf, vTb, Eb, attnb);

  final_gemm<<<dim3(64, 4, 1), 256, 0, stream>>>(attnb, fcwb, fcb, (float*)d_out);
}

// Round 7
// 268.799 us; speedup vs baseline: 1.3099x; 1.3099x over previous
//
#include <hip/hip_runtime.h>
#include <stdint.h>

typedef __bf16 bf16;
typedef float f32x4 __attribute__((ext_vector_type(4)));
typedef bf16 bf16x8 __attribute__((ext_vector_type(8)));
typedef bf16 bf16x4 __attribute__((ext_vector_type(4)));

#define MFMA16(a, b, c) __builtin_amdgcn_mfma_f32_16x16x32_bf16((a), (b), (c), 0, 0, 0)
#define EXP2F(x) __builtin_amdgcn_exp2f(x)

__device__ __forceinline__ void gll16(const void* g, void* l) {
  __builtin_amdgcn_global_load_lds((const __attribute__((address_space(1))) void*)g,
                                   (__attribute__((address_space(3))) void*)l, 16, 0, 0);
}

// ---------------------------------------------------------------------------
// fp32 -> bf16 conversion of all tensors, one launch.
// ---------------------------------------------------------------------------
__global__ __launch_bounds__(256) void convert_all(
    const float4* __restrict__ Q, const float4* __restrict__ K, const float4* __restrict__ V,
    const float4* __restrict__ Wq, const float4* __restrict__ Wk, const float4* __restrict__ Wv,
    const float4* __restrict__ fcw, const float4* __restrict__ E,
    bf16x4* __restrict__ Xq, bf16x4* __restrict__ Xk, bf16x4* __restrict__ Xv,
    bf16x4* __restrict__ Wqb, bf16x4* __restrict__ Wkb, bf16x4* __restrict__ Wvb,
    bf16x4* __restrict__ fcb, bf16x4* __restrict__ Eb) {
  int i = blockIdx.x * 256 + threadIdx.x;
  const float4* s;
  bf16x4* d;
  int off;
  if (i < 1048576) { s = Q; d = Xq; off = i; }
  else if (i < 2097152) { s = K; d = Xk; off = i - 1048576; }
  else if (i < 3145728) { s = V; d = Xv; off = i - 2097152; }
  else if (i < 3211264) { s = Wq; d = Wqb; off = i - 3145728; }
  else if (i < 3276800) { s = Wk; d = Wkb; off = i - 3211264; }
  else if (i < 3342336) { s = Wv; d = Wvb; off = i - 3276800; }
  else if (i < 3407872) { s = fcw; d = fcb; off = i - 3342336; }
  else { s = E; d = Eb; off = i - 3407872; }
  float4 v = s[off];
  bf16x4 o;
  o[0] = (bf16)v.x; o[1] = (bf16)v.y; o[2] = (bf16)v.z; o[3] = (bf16)v.w;
  d[off] = o;
}

// ---------------------------------------------------------------------------
// GEMM core: C[128x128] = A[128x512] * Bt[128x512]^T (row-major bf16).
// ---------------------------------------------------------------------------
__device__ __forceinline__ void gemm_core(const bf16* __restrict__ A, const bf16* __restrict__ Bt,
                                          bf16* ldsA, bf16* ldsB, int m0, int n0,
                                          f32x4 acc[4][4]) {
  const int t = threadIdx.x;
  const int lane = t & 63, w = t >> 6;
  const int l15 = lane & 15, quad = lane >> 4;
  const int wm = w >> 1, wn = w & 1;
#pragma unroll
  for (int i = 0; i < 4; i++)
#pragma unroll
    for (int j = 0; j < 4; j++) acc[i][j] = (f32x4){0.f, 0.f, 0.f, 0.f};

  const int ch0 = t, ch1 = t + 256;
  const int r0 = ch0 >> 2, c0 = (ch0 & 3) ^ (r0 & 3);
  const int r1 = ch1 >> 2, c1 = (ch1 & 3) ^ (r1 & 3);

  int aoff[4], boff[4];
#pragma unroll
  for (int mt = 0; mt < 4; mt++) {
    int m = wm * 64 + mt * 16 + l15;
    aoff[mt] = (m << 6) + ((quad ^ (l15 & 3)) << 4);
    int n = wn * 64 + mt * 16 + l15;
    boff[mt] = (n << 6) + ((quad ^ (l15 & 3)) << 4);
  }
  bf16* ldsA1 = ldsA + w * 512;
  bf16* ldsA2 = ldsA + 2048 + w * 512;
  bf16* ldsB1 = ldsB + w * 512;
  bf16* ldsB2 = ldsB + 2048 + w * 512;

  for (int kt = 0; kt < 512; kt += 32) {
    gll16(A + (size_t)(m0 + r0) * 512 + kt + c0 * 8, ldsA1);
    gll16(A + (size_t)(m0 + r1) * 512 + kt + c1 * 8, ldsA2);
    gll16(Bt + (size_t)(n0 + r0) * 512 + kt + c0 * 8, ldsB1);
    gll16(Bt + (size_t)(n0 + r1) * 512 + kt + c1 * 8, ldsB2);
    __syncthreads();
    bf16x8 af[4], bfr[4];
#pragma unroll
    for (int mt = 0; mt < 4; mt++) af[mt] = *(const bf16x8*)((const char*)ldsA + aoff[mt]);
#pragma unroll
    for (int nt = 0; nt < 4; nt++) bfr[nt] = *(const bf16x8*)((const char*)ldsB + boff[nt]);
#pragma unroll
    for (int mt = 0; mt < 4; mt++)
#pragma unroll
      for (int nt = 0; nt < 4; nt++)
        acc[mt][nt] = MFMA16(af[mt], bfr[nt], acc[mt][nt]);
    __syncthreads();
  }
}

__global__ __launch_bounds__(256) void proj_gemm(
    const bf16* __restrict__ Xq, const bf16* __restrict__ Xk, const bf16* __restrict__ Xv,
    const bf16* __restrict__ Wq, const bf16* __restrict__ Wk, const bf16* __restrict__ Wv,
    const float* __restrict__ bq, const float* __restrict__ bk, const float* __restrict__ bv,
    bf16* __restrict__ qb, bf16* __restrict__ kb, bf16* __restrict__ vb) {
  __shared__ bf16 ldsA[128 * 32];
  __shared__ bf16 ldsB[128 * 32];
  const int z = blockIdx.z;
  const bf16* A = z == 0 ? Xq : (z == 1 ? Xk : Xv);
  const bf16* W = z == 0 ? Wq : (z == 1 ? Wk : Wv);
  const float* bias = z == 0 ? bq : (z == 1 ? bk : bv);
  bf16* out = z == 0 ? qb : (z == 1 ? kb : vb);
  const int m0 = blockIdx.x * 128, n0 = blockIdx.y * 128;
  f32x4 acc[4][4];
  gemm_core(A, W, ldsA, ldsB, m0, n0, acc);

  const int t = threadIdx.x;
  const int lane = t & 63, w = t >> 6;
  const int l15 = lane & 15, quad = lane >> 4;
  const int wm = w >> 1, wn = w & 1;
#pragma unroll
  for (int mt = 0; mt < 4; mt++)
#pragma unroll
    for (int nt = 0; nt < 4; nt++)
#pragma unroll
      for (int r = 0; r < 4; r++) {
        int gm = m0 + wm * 64 + mt * 16 + quad * 4 + r;
        int gn = n0 + wn * 64 + nt * 16 + l15;
        float v = acc[mt][nt][r] + bias[gn];
        int b = gm >> 11, l = gm & 2047, h = gn >> 6, d = gn & 63;
        out[(((size_t)(b * 8 + h)) * 2048 + l) * 64 + d] = (bf16)v;
      }
}

__global__ __launch_bounds__(256) void final_gemm(const bf16* __restrict__ A,
                                                  const bf16* __restrict__ W,
                                                  const float* __restrict__ bias,
                                                  float* __restrict__ out) {
  __shared__ bf16 ldsA[128 * 32];
  __shared__ bf16 ldsB[128 * 32];
  const int m0 = blockIdx.x * 128, n0 = blockIdx.y * 128;
  f32x4 acc[4][4];
  gemm_core(A, W, ldsA, ldsB, m0, n0, acc);

  const int t = threadIdx.x;
  const int lane = t & 63, w = t >> 6;
  const int l15 = lane & 15, quad = lane >> 4;
  const int wm = w >> 1, wn = w & 1;
#pragma unroll
  for (int mt = 0; mt < 4; mt++)
#pragma unroll
    for (int nt = 0; nt < 4; nt++)
#pragma unroll
      for (int r = 0; r < 4; r++) {
        int gm = m0 + wm * 64 + mt * 16 + quad * 4 + r;
        int gn = n0 + wn * 64 + nt * 16 + l15;
        out[(size_t)gm * 512 + gn] = acc[mt][nt][r] + bias[gn];
      }
}

// v (B,H,L,64) -> vT (B,H,64,L)
__global__ __launch_bounds__(256) void transpose_v(const bf16* __restrict__ vbuf,
                                                   bf16* __restrict__ vT) {
  __shared__ bf16 tile[64][72];
  const int bh = blockIdx.y, l0 = blockIdx.x * 64;
  const bf16* src = vbuf + ((size_t)bh * 2048 + l0) * 64;
  bf16* dst = vT + (size_t)bh * 64 * 2048 + l0;
  const int t = threadIdx.x;
#pragma unroll
  for (int p = 0; p < 2; p++) {
    int ch = t + p * 256;
    int r = ch >> 3, c8 = ch & 7;
    *(bf16x8*)&tile[r][c8 * 8] = *(const bf16x8*)&src[(size_t)r * 64 + c8 * 8];
  }
  __syncthreads();
#pragma unroll
  for (int p = 0; p < 2; p++) {
    int ch = t + p * 256;
    int dr = ch >> 3, lc = ch & 7;
    bf16x8 v;
#pragma unroll
    for (int j = 0; j < 8; j++) v[j] = tile[lc * 8 + j][dr];
    *(bf16x8*)&dst[(size_t)dr * 2048 + lc * 8] = v;
  }
}

// ---------------------------------------------------------------------------
// Flash attention + relative position, causal. Max-free unnormalized softmax.
// Block = 4 waves x 16 q-rows = 64 rows; all waves run the same t4+1 j-tiles.
// K/V tiles staged block-cooperatively into a SINGLE 16 KB LDS buffer via
// global_load_lds (swizzled); 2 barriers per tile, with the E-band T-MFMA
// (global loads, LDS-free) placed between staging-issue and the consuming
// barrier. Skew gather done IN REGISTERS via ds_bpermute (crossbar, no bank
// conflicts): T[u'][c'=j+15-u'] lives at the same reg r and quad as the
// consumer; only the low-4 lane rotates, tile = nt or nt+1 (cndmask).
// Grid 1024 phase-paired -> 4 blocks/CU, 66 tile-loops per CU.
// ---------------------------------------------------------------------------
__global__ __launch_bounds__(256, 4) void attn_kernel(const bf16* __restrict__ qbuf,
                                                      const bf16* __restrict__ kbuf,
                                                      const bf16* __restrict__ vT,
                                                      const bf16* __restrict__ Eb,
                                                      bf16* __restrict__ attn) {
  __shared__ bf16 Kl[64 * 64];
  __shared__ bf16 Vl[64 * 64];
  __shared__ bf16 Pl[4][16 * 72];
  const int t = threadIdx.x, w = t >> 6, lane = t & 63;
  const int l15 = lane & 15, quad = lane >> 4;
  const int x = blockIdx.x;
  const int pid = x & 511, phase = x >> 9;
  const int a = pid & 15, bh = pid >> 4;
  const int t4 = phase ? a : 31 - a;  // strip index; heavy strips dispatched first
  const int i0 = t4 * 64 + w * 16;    // this wave's 16 q-rows
  bf16* Pw = Pl[w];
  const bf16* qh = qbuf + (size_t)bh * 2048 * 64;
  const bf16* kh = kbuf + (size_t)bh * 2048 * 64;
  const bf16* vh = vT + (size_t)bh * 64 * 2048;

  // staging: slot s holds (row = s>>3, chunk = (s&7)^(row&7)); thread t does
  // slots t and t+256; wave-uniform LDS dest = slot-group base + lane*16B.
  const int sr0 = t >> 3, sc0 = (t & 7) ^ (sr0 & 7);
  const int sr1 = sr0 + 32;  // (t+256)>>3 ; chunk swizzle unchanged (32&7==0)
  const int wb0 = (t & 192) * 8;
  const int wb1 = 2048 + wb0;

  // bpermute lane addresses + tile-select mask, per acc register r
  int bpaddr[4];
  bool loA[4];
#pragma unroll
  for (int r = 0; r < 4; r++) {
    int u = quad * 4 + r;
    bpaddr[r] = (((l15 + 15 - u) & 15) + 16 * quad) * 4;
    loA[r] = (l15 <= u);  // d = l15+15-u < 16  -> source tile nt (else nt+1)
  }

  bf16x8 aq0, aq1;
  {
    const bf16* qrow = qh + (size_t)(i0 + l15) * 64 + quad * 8;
    aq0 = *(const bf16x8*)qrow;
    aq1 = *(const bf16x8*)(qrow + 32);
  }
  bf16x8 ones;
#pragma unroll
  for (int j = 0; j < 8; j++) ones[j] = (bf16)1.0f;

  f32x4 O[4], Osum;
  Osum = (f32x4){0.f, 0.f, 0.f, 0.f};
#pragma unroll
  for (int i = 0; i < 4; i++) O[i] = (f32x4){0.f, 0.f, 0.f, 0.f};
  const float sc = 0.125f * 1.44269504088896f;  // 1/sqrt(64) * log2(e)

  for (int jt = 0; jt <= t4; jt++) {
    const int j0 = jt * 64;
    const bool diag = (jt == t4);  // only the last tile touches the diagonal
    __syncthreads();  // all waves done reading K/V of previous tile
    // ---- issue staging for this tile (async into LDS) ----
    gll16(kh + (size_t)(j0 + sr0) * 64 + sc0 * 8, (char*)Kl + wb0 * 2);
    gll16(kh + (size_t)(j0 + sr1) * 64 + sc0 * 8, (char*)Kl + wb1 * 2);
    gll16(vh + (size_t)sr0 * 2048 + j0 + sc0 * 8, (char*)Vl + wb0 * 2);
    gll16(vh + (size_t)sr1 * 2048 + j0 + sc0 * 8, (char*)Vl + wb1 * 2);
    // ---- T band (16x80) via MFMA from global E (overlaps staging) ----
    const int ebase = 2047 - i0 + j0 - 15;
    f32x4 z[5];
#pragma unroll
    for (int nt = 0; nt < 5; nt++) {
      int er = ebase + nt * 16 + l15;
      er = er > 2047 ? 2047 : er;  // clamped rows feed only masked entries
      const bf16* erow = Eb + (size_t)er * 64 + quad * 8;
      bf16x8 b0 = *(const bf16x8*)erow;
      bf16x8 b1 = *(const bf16x8*)(erow + 32);
      f32x4 zz = (f32x4){0.f, 0.f, 0.f, 0.f};
      zz = MFMA16(aq0, b0, zz);
      z[nt] = MFMA16(aq1, b1, zz);
    }
    // ---- in-register skew gather: crossbar bpermute, no bank conflicts ----
    float Bp[5][4];
#pragma unroll
    for (int tn = 0; tn < 5; tn++)
#pragma unroll
      for (int r = 0; r < 4; r++)
        Bp[tn][r] = __int_as_float(
            __builtin_amdgcn_ds_bpermute(bpaddr[r], __float_as_int(z[tn][r])));
    __syncthreads();  // staging complete (vmcnt drained by compiler)
    // ---- S = q @ k^T from LDS (swizzled b128 reads) ----
    f32x4 s[4];
#pragma unroll
    for (int nt = 0; nt < 4; nt++) {
      int row = nt * 16 + l15;
      bf16x8 b0 = *(const bf16x8*)(Kl + ((row << 3) + (quad ^ (row & 7))) * 8);
      bf16x8 b1 = *(const bf16x8*)(Kl + ((row << 3) + ((quad + 4) ^ (row & 7))) * 8);
      f32x4 zz = (f32x4){0.f, 0.f, 0.f, 0.f};
      zz = MFMA16(aq0, b0, zz);
      s[nt] = MFMA16(aq1, b1, zz);
    }
    // ---- logits: skew add + scale (+ mask on diag tile) + exp2 + P ----
    if (diag) {
#pragma unroll
      for (int nt = 0; nt < 4; nt++)
#pragma unroll
        for (int r = 0; r < 4; r++) {
          int u = quad * 4 + r;
          int j = nt * 16 + l15;
          float skew = loA[r] ? Bp[nt][r] : Bp[nt + 1][r];
          float logit = (s[nt][r] + skew) * sc;
          if (j0 + j > i0 + u) logit = -1e30f;  // causal; exp2 -> 0
          Pw[u * 72 + j] = (bf16)EXP2F(logit);
        }
    } else {
#pragma unroll
      for (int nt = 0; nt < 4; nt++)
#pragma unroll
        for (int r = 0; r < 4; r++) {
          int u = quad * 4 + r;
          int j = nt * 16 + l15;
          float skew = loA[r] ? Bp[nt][r] : Bp[nt + 1][r];
          Pw[u * 72 + j] = (bf16)EXP2F((s[nt][r] + skew) * sc);
        }
    }
    // ---- PV: O += P @ V ; Osum += P @ ones ----
    bf16x8 pa0 = *(const bf16x8*)&Pw[l15 * 72 + quad * 8];
    bf16x8 pa1 = *(const bf16x8*)&Pw[l15 * 72 + 32 + quad * 8];
    Osum = MFMA16(pa0, ones, Osum);
    Osum = MFMA16(pa1, ones, Osum);
#pragma unroll
    for (int nt = 0; nt < 4; nt++) {
      int row = nt * 16 + l15;
      bf16x8 b0 = *(const bf16x8*)(Vl + ((row << 3) + (quad ^ (row & 7))) * 8);
      bf16x8 b1 = *(const bf16x8*)(Vl + ((row << 3) + ((quad + 4) ^ (row & 7))) * 8);
      O[nt] = MFMA16(pa0, b0, O[nt]);
      O[nt] = MFMA16(pa1, b1, O[nt]);
    }
  }
  // ---- epilogue: O / rowsum, write (B,L,H*DH) bf16 ----
  const int b = bh >> 3, hh = bh & 7;
  float inv[4];
#pragma unroll
  for (int r = 0; r < 4; r++) inv[r] = 1.0f / Osum[r];
  bf16* orow = attn + ((size_t)(b * 2048 + i0)) * 512 + hh * 64;
#pragma unroll
  for (int nt = 0; nt < 4; nt++)
#pragma unroll
    for (int r = 0; r < 4; r++)
      orow[(size_t)(quad * 4 + r) * 512 + nt * 16 + l15] = (bf16)(O[nt][r] * inv[r]);
}

// ---------------------------------------------------------------------------
extern "C" void kernel_launch(void* const* d_in, const int* in_sizes, int n_in,
                              void* d_out, int out_size, void* d_ws, size_t ws_size,
                              hipStream_t stream) {
  const float* Q = (const float*)d_in[0];
  const float* K = (const float*)d_in[1];
  const float* V = (const float*)d_in[2];
  const float* Wq = (const float*)d_in[4];
  const float* bq = (const float*)d_in[5];
  const float* Wk = (const float*)d_in[6];
  const float* bk = (const float*)d_in[7];
  const float* Wv = (const float*)d_in[8];
  const float* bv = (const float*)d_in[9];
  const float* fcw = (const float*)d_in[10];
  const float* fcb = (const float*)d_in[11];
  const float* E = (const float*)d_in[12];

  char* ws = (char*)d_ws;
  bf16* Xq = (bf16*)(ws + 0);
  bf16* Xk = (bf16*)(ws + 8388608);
  bf16* Xv = (bf16*)(ws + 16777216);
  bf16* Wqb = (bf16*)(ws + 25165824);
  bf16* Wkb = (bf16*)(ws + 25690112);
  bf16* Wvb = (bf16*)(ws + 26214400);
  bf16* fcwb = (bf16*)(ws + 26738688);
  bf16* Eb = (bf16*)(ws + 27262976);
  bf16* qbuf = (bf16*)(ws + 27525120);
  bf16* kbuf = (bf16*)(ws + 35913728);
  bf16* vbuf = (bf16*)(ws + 44302336);
  bf16* vTb = Xk;
  bf16* attnb = Xq;

  convert_all<<<13440, 256, 0, stream>>>(
      (const float4*)Q, (const float4*)K, (const float4*)V, (const float4*)Wq,
      (const float4*)Wk, (const float4*)Wv, (const float4*)fcw, (const float4*)E,
      (bf16x4*)Xq, (bf16x4*)Xk, (bf16x4*)Xv, (bf16x4*)Wqb, (bf16x4*)Wkb,
      (bf16x4*)Wvb, (bf16x4*)fcwb, (bf16x4*)Eb);

  proj_gemm<<<dim3(64, 4, 3), 256, 0, stream>>>(Xq, Xk, Xv, Wqb, Wkb, Wvb, bq, bk, bv,
                                                qbuf, kbuf, vbuf);

  transpose_v<<<dim3(32, 32), 256, 0, stream>>>(vbuf, vTb);

  attn_kernel<<<1024, 256, 0, stream>>>(qbuf, kbuf, vTb, Eb, attnb);

  final_gemm<<<dim3(64, 4, 1), 256, 0, stream>>>(attnb, fcwb, fcb, (float*)d_out);
}

// Round 8
// 250.906 us; speedup vs baseline: 1.4033x; 1.0713x over previous
//
#include <hip/hip_runtime.h>
#include <stdint.h>

typedef __bf16 bf16;
typedef float f32x4 __attribute__((ext_vector_type(4)));
typedef bf16 bf16x8 __attribute__((ext_vector_type(8)));
typedef bf16 bf16x4 __attribute__((ext_vector_type(4)));

#define MFMA16(a, b, c) __builtin_amdgcn_mfma_f32_16x16x32_bf16((a), (b), (c), 0, 0, 0)
#define EXP2F(x) __builtin_amdgcn_exp2f(x)

__device__ __forceinline__ void gll16(const void* g, void* l) {
  __builtin_amdgcn_global_load_lds((const __attribute__((address_space(1))) void*)g,
                                   (__attribute__((address_space(3))) void*)l, 16, 0, 0);
}

// ---------------------------------------------------------------------------
// fp32 -> bf16 conversion of all tensors, one launch.
// ---------------------------------------------------------------------------
__global__ __launch_bounds__(256) void convert_all(
    const float4* __restrict__ Q, const float4* __restrict__ K, const float4* __restrict__ V,
    const float4* __restrict__ Wq, const float4* __restrict__ Wk, const float4* __restrict__ Wv,
    const float4* __restrict__ fcw, const float4* __restrict__ E,
    bf16x4* __restrict__ Xq, bf16x4* __restrict__ Xk, bf16x4* __restrict__ Xv,
    bf16x4* __restrict__ Wqb, bf16x4* __restrict__ Wkb, bf16x4* __restrict__ Wvb,
    bf16x4* __restrict__ fcb, bf16x4* __restrict__ Eb) {
  int i = blockIdx.x * 256 + threadIdx.x;
  const float4* s;
  bf16x4* d;
  int off;
  if (i < 1048576) { s = Q; d = Xq; off = i; }
  else if (i < 2097152) { s = K; d = Xk; off = i - 1048576; }
  else if (i < 3145728) { s = V; d = Xv; off = i - 2097152; }
  else if (i < 3211264) { s = Wq; d = Wqb; off = i - 3145728; }
  else if (i < 3276800) { s = Wk; d = Wkb; off = i - 3211264; }
  else if (i < 3342336) { s = Wv; d = Wvb; off = i - 3276800; }
  else if (i < 3407872) { s = fcw; d = fcb; off = i - 3342336; }
  else { s = E; d = Eb; off = i - 3407872; }
  float4 v = s[off];
  bf16x4 o;
  o[0] = (bf16)v.x; o[1] = (bf16)v.y; o[2] = (bf16)v.z; o[3] = (bf16)v.w;
  d[off] = o;
}

// ---------------------------------------------------------------------------
// GEMM core: C[128x128] = A[128x512] * Bt[128x512]^T (row-major bf16).
// ---------------------------------------------------------------------------
__device__ __forceinline__ void gemm_core(const bf16* __restrict__ A, const bf16* __restrict__ Bt,
                                          bf16* ldsA, bf16* ldsB, int m0, int n0,
                                          f32x4 acc[4][4]) {
  const int t = threadIdx.x;
  const int lane = t & 63, w = t >> 6;
  const int l15 = lane & 15, quad = lane >> 4;
  const int wm = w >> 1, wn = w & 1;
#pragma unroll
  for (int i = 0; i < 4; i++)
#pragma unroll
    for (int j = 0; j < 4; j++) acc[i][j] = (f32x4){0.f, 0.f, 0.f, 0.f};

  const int ch0 = t, ch1 = t + 256;
  const int r0 = ch0 >> 2, c0 = (ch0 & 3) ^ (r0 & 3);
  const int r1 = ch1 >> 2, c1 = (ch1 & 3) ^ (r1 & 3);

  int aoff[4], boff[4];
#pragma unroll
  for (int mt = 0; mt < 4; mt++) {
    int m = wm * 64 + mt * 16 + l15;
    aoff[mt] = (m << 6) + ((quad ^ (l15 & 3)) << 4);
    int n = wn * 64 + mt * 16 + l15;
    boff[mt] = (n << 6) + ((quad ^ (l15 & 3)) << 4);
  }
  bf16* ldsA1 = ldsA + w * 512;
  bf16* ldsA2 = ldsA + 2048 + w * 512;
  bf16* ldsB1 = ldsB + w * 512;
  bf16* ldsB2 = ldsB + 2048 + w * 512;

  for (int kt = 0; kt < 512; kt += 32) {
    gll16(A + (size_t)(m0 + r0) * 512 + kt + c0 * 8, ldsA1);
    gll16(A + (size_t)(m0 + r1) * 512 + kt + c1 * 8, ldsA2);
    gll16(Bt + (size_t)(n0 + r0) * 512 + kt + c0 * 8, ldsB1);
    gll16(Bt + (size_t)(n0 + r1) * 512 + kt + c1 * 8, ldsB2);
    __syncthreads();
    bf16x8 af[4], bfr[4];
#pragma unroll
    for (int mt = 0; mt < 4; mt++) af[mt] = *(const bf16x8*)((const char*)ldsA + aoff[mt]);
#pragma unroll
    for (int nt = 0; nt < 4; nt++) bfr[nt] = *(const bf16x8*)((const char*)ldsB + boff[nt]);
#pragma unroll
    for (int mt = 0; mt < 4; mt++)
#pragma unroll
      for (int nt = 0; nt < 4; nt++)
        acc[mt][nt] = MFMA16(af[mt], bfr[nt], acc[mt][nt]);
    __syncthreads();
  }
}

__global__ __launch_bounds__(256) void proj_gemm(
    const bf16* __restrict__ Xq, const bf16* __restrict__ Xk, const bf16* __restrict__ Xv,
    const bf16* __restrict__ Wq, const bf16* __restrict__ Wk, const bf16* __restrict__ Wv,
    const float* __restrict__ bq, const float* __restrict__ bk, const float* __restrict__ bv,
    bf16* __restrict__ qb, bf16* __restrict__ kb, bf16* __restrict__ vb) {
  __shared__ bf16 ldsA[128 * 32];
  __shared__ bf16 ldsB[128 * 32];
  const int z = blockIdx.z;
  const bf16* A = z == 0 ? Xq : (z == 1 ? Xk : Xv);
  const bf16* W = z == 0 ? Wq : (z == 1 ? Wk : Wv);
  const float* bias = z == 0 ? bq : (z == 1 ? bk : bv);
  bf16* out = z == 0 ? qb : (z == 1 ? kb : vb);
  const int m0 = blockIdx.x * 128, n0 = blockIdx.y * 128;
  f32x4 acc[4][4];
  gemm_core(A, W, ldsA, ldsB, m0, n0, acc);

  const int t = threadIdx.x;
  const int lane = t & 63, w = t >> 6;
  const int l15 = lane & 15, quad = lane >> 4;
  const int wm = w >> 1, wn = w & 1;
#pragma unroll
  for (int mt = 0; mt < 4; mt++)
#pragma unroll
    for (int nt = 0; nt < 4; nt++)
#pragma unroll
      for (int r = 0; r < 4; r++) {
        int gm = m0 + wm * 64 + mt * 16 + quad * 4 + r;
        int gn = n0 + wn * 64 + nt * 16 + l15;
        float v = acc[mt][nt][r] + bias[gn];
        int b = gm >> 11, l = gm & 2047, h = gn >> 6, d = gn & 63;
        out[(((size_t)(b * 8 + h)) * 2048 + l) * 64 + d] = (bf16)v;
      }
}

__global__ __launch_bounds__(256) void final_gemm(const bf16* __restrict__ A,
                                                  const bf16* __restrict__ W,
                                                  const float* __restrict__ bias,
                                                  float* __restrict__ out) {
  __shared__ bf16 ldsA[128 * 32];
  __shared__ bf16 ldsB[128 * 32];
  const int m0 = blockIdx.x * 128, n0 = blockIdx.y * 128;
  f32x4 acc[4][4];
  gemm_core(A, W, ldsA, ldsB, m0, n0, acc);

  const int t = threadIdx.x;
  const int lane = t & 63, w = t >> 6;
  const int l15 = lane & 15, quad = lane >> 4;
  const int wm = w >> 1, wn = w & 1;
#pragma unroll
  for (int mt = 0; mt < 4; mt++)
#pragma unroll
    for (int nt = 0; nt < 4; nt++)
#pragma unroll
      for (int r = 0; r < 4; r++) {
        int gm = m0 + wm * 64 + mt * 16 + quad * 4 + r;
        int gn = n0 + wn * 64 + nt * 16 + l15;
        out[(size_t)gm * 512 + gn] = acc[mt][nt][r] + bias[gn];
      }
}

// v (B,H,L,64) -> vT (B,H,64,L)
__global__ __launch_bounds__(256) void transpose_v(const bf16* __restrict__ vbuf,
                                                   bf16* __restrict__ vT) {
  __shared__ bf16 tile[64][72];
  const int bh = blockIdx.y, l0 = blockIdx.x * 64;
  const bf16* src = vbuf + ((size_t)bh * 2048 + l0) * 64;
  bf16* dst = vT + (size_t)bh * 64 * 2048 + l0;
  const int t = threadIdx.x;
#pragma unroll
  for (int p = 0; p < 2; p++) {
    int ch = t + p * 256;
    int r = ch >> 3, c8 = ch & 7;
    *(bf16x8*)&tile[r][c8 * 8] = *(const bf16x8*)&src[(size_t)r * 64 + c8 * 8];
  }
  __syncthreads();
#pragma unroll
  for (int p = 0; p < 2; p++) {
    int ch = t + p * 256;
    int dr = ch >> 3, lc = ch & 7;
    bf16x8 v;
#pragma unroll
    for (int j = 0; j < 8; j++) v[j] = tile[lc * 8 + j][dr];
    *(bf16x8*)&dst[(size_t)dr * 2048 + lc * 8] = v;
  }
}

// ---------------------------------------------------------------------------
// Flash attention + relative position, causal. Max-free unnormalized softmax.
// Block = 4 waves x 16 q-rows = 64 rows; all waves run the same t4+1 j-tiles.
// K/V tiles DOUBLE-BUFFERED in LDS via global_load_lds: staging for tile jt+1
// is issued right after the single per-tile barrier and consumed a full
// tile-loop later -> barrier's vmcnt(0) drain is already satisfied.
// E-band via MFMA from global; the 5th T-tile of tile jt == 1st of jt+1, so
// its bpermuted skew (Bp[4]) is carried -> 8 loads/8 MFMA/16 bperm per tile.
// Skew gather via ds_bpermute crossbar (conflict-free). Grid 1024, LPT order
// (heavy strips first), 3 blocks/CU resident + refills -> balanced.
// ---------------------------------------------------------------------------
__global__ __launch_bounds__(256, 3) void attn_kernel(const bf16* __restrict__ qbuf,
                                                      const bf16* __restrict__ kbuf,
                                                      const bf16* __restrict__ vT,
                                                      const bf16* __restrict__ Eb,
                                                      bf16* __restrict__ attn) {
  __shared__ bf16 Kl[2][64 * 64];
  __shared__ bf16 Vl[2][64 * 64];
  __shared__ bf16 Pl[4][16 * 72];
  const int t = threadIdx.x, w = t >> 6, lane = t & 63;
  const int l15 = lane & 15, quad = lane >> 4;
  const int x = blockIdx.x;
  const int pid = x & 511, phase = x >> 9;
  const int a = pid & 15, bh = pid >> 4;
  const int t4 = phase ? a : 31 - a;  // strip index; heavy strips dispatched first
  const int i0 = t4 * 64 + w * 16;    // this wave's 16 q-rows
  bf16* Pw = Pl[w];
  const bf16* qh = qbuf + (size_t)bh * 2048 * 64;
  const bf16* kh = kbuf + (size_t)bh * 2048 * 64;
  const bf16* vh = vT + (size_t)bh * 64 * 2048;

  // staging: slot s holds (row = s>>3, chunk = (s&7)^(row&7)); thread t does
  // slots t and t+256; wave-uniform LDS byte base + lane*16B.
  const int sr0 = t >> 3, sc0 = (t & 7) ^ (sr0 & 7);
  const int sr1 = sr0 + 32;
  const int b0 = (t & 192) * 16;  // byte offset of this wave's slot group
  const int b1 = 4096 + b0;

  // bpermute lane addresses + tile-select mask, per acc register r
  int bpaddr[4];
  bool loA[4];
#pragma unroll
  for (int r = 0; r < 4; r++) {
    int u = quad * 4 + r;
    bpaddr[r] = (((l15 + 15 - u) & 15) + 16 * quad) * 4;
    loA[r] = (l15 <= u);  // source tile nt (else nt+1)
  }

  bf16x8 aq0, aq1;
  {
    const bf16* qrow = qh + (size_t)(i0 + l15) * 64 + quad * 8;
    aq0 = *(const bf16x8*)qrow;
    aq1 = *(const bf16x8*)(qrow + 32);
  }
  bf16x8 ones;
#pragma unroll
  for (int j = 0; j < 8; j++) ones[j] = (bf16)1.0f;

  f32x4 O[4], Osum;
  Osum = (f32x4){0.f, 0.f, 0.f, 0.f};
#pragma unroll
  for (int i = 0; i < 4; i++) O[i] = (f32x4){0.f, 0.f, 0.f, 0.f};
  const float sc = 0.125f * 1.44269504088896f;  // 1/sqrt(64) * log2(e)
  const int ebase0 = 2047 - i0 - 15;

  // ---- prologue: stage tile 0 into buffer 0 ----
  gll16(kh + (size_t)sr0 * 64 + sc0 * 8, (char*)&Kl[0][0] + b0);
  gll16(kh + (size_t)sr1 * 64 + sc0 * 8, (char*)&Kl[0][0] + b1);
  gll16(vh + (size_t)sr0 * 2048 + sc0 * 8, (char*)&Vl[0][0] + b0);
  gll16(vh + (size_t)sr1 * 2048 + sc0 * 8, (char*)&Vl[0][0] + b1);

  // ---- carry init: T-tile nt=0 of jt=0 ----
  float Bpc[4];
  {
    int er = ebase0 + l15;
    er = er > 2047 ? 2047 : er;
    const bf16* erow = Eb + (size_t)er * 64 + quad * 8;
    bf16x8 e0 = *(const bf16x8*)erow;
    bf16x8 e1 = *(const bf16x8*)(erow + 32);
    f32x4 zz = (f32x4){0.f, 0.f, 0.f, 0.f};
    zz = MFMA16(aq0, e0, zz);
    zz = MFMA16(aq1, e1, zz);
#pragma unroll
    for (int r = 0; r < 4; r++)
      Bpc[r] = __int_as_float(__builtin_amdgcn_ds_bpermute(bpaddr[r], __float_as_int(zz[r])));
  }

  for (int jt = 0; jt <= t4; jt++) {
    const int j0 = jt * 64;
    const int cur = jt & 1;
    const bool diag = (jt == t4);
    // ---- E-band for this tile: fresh T-tiles nt=1..4 (nt=0 carried) ----
    float Bp[5][4];
#pragma unroll
    for (int r = 0; r < 4; r++) Bp[0][r] = Bpc[r];
    const int ebase = ebase0 + j0;
#pragma unroll
    for (int nt = 1; nt < 5; nt++) {
      int er = ebase + nt * 16 + l15;
      er = er > 2047 ? 2047 : er;  // clamped rows feed only masked entries
      const bf16* erow = Eb + (size_t)er * 64 + quad * 8;
      bf16x8 e0 = *(const bf16x8*)erow;
      bf16x8 e1 = *(const bf16x8*)(erow + 32);
      f32x4 zz = (f32x4){0.f, 0.f, 0.f, 0.f};
      zz = MFMA16(aq0, e0, zz);
      zz = MFMA16(aq1, e1, zz);
#pragma unroll
      for (int r = 0; r < 4; r++)
        Bp[nt][r] =
            __int_as_float(__builtin_amdgcn_ds_bpermute(bpaddr[r], __float_as_int(zz[r])));
    }
#pragma unroll
    for (int r = 0; r < 4; r++) Bpc[r] = Bp[4][r];

    __syncthreads();  // staging(jt) complete (issued a full tile ago); waves joined
    // ---- issue staging for tile jt+1 into the other buffer ----
    if (jt < t4) {
      const int nb = cur ^ 1, nj = j0 + 64;
      gll16(kh + (size_t)(nj + sr0) * 64 + sc0 * 8, (char*)&Kl[nb][0] + b0);
      gll16(kh + (size_t)(nj + sr1) * 64 + sc0 * 8, (char*)&Kl[nb][0] + b1);
      gll16(vh + (size_t)sr0 * 2048 + nj + sc0 * 8, (char*)&Vl[nb][0] + b0);
      gll16(vh + (size_t)sr1 * 2048 + nj + sc0 * 8, (char*)&Vl[nb][0] + b1);
    }
    const bf16* Kc = Kl[cur];
    const bf16* Vc = Vl[cur];
    // ---- S = q @ k^T from LDS (swizzled b128 reads) ----
    f32x4 s[4];
#pragma unroll
    for (int nt = 0; nt < 4; nt++) {
      int row = nt * 16 + l15;
      bf16x8 k0 = *(const bf16x8*)(Kc + ((row << 3) + (quad ^ (row & 7))) * 8);
      bf16x8 k1 = *(const bf16x8*)(Kc + ((row << 3) + ((quad + 4) ^ (row & 7))) * 8);
      f32x4 zz = (f32x4){0.f, 0.f, 0.f, 0.f};
      zz = MFMA16(aq0, k0, zz);
      s[nt] = MFMA16(aq1, k1, zz);
    }
    // ---- logits: skew add + scale (+ mask on diag tile) + exp2 + P ----
    if (diag) {
#pragma unroll
      for (int nt = 0; nt < 4; nt++)
#pragma unroll
        for (int r = 0; r < 4; r++) {
          int u = quad * 4 + r;
          int j = nt * 16 + l15;
          float skew = loA[r] ? Bp[nt][r] : Bp[nt + 1][r];
          float logit = (s[nt][r] + skew) * sc;
          if (j0 + j > i0 + u) logit = -1e30f;  // causal; exp2 -> 0
          Pw[u * 72 + j] = (bf16)EXP2F(logit);
        }
    } else {
#pragma unroll
      for (int nt = 0; nt < 4; nt++)
#pragma unroll
        for (int r = 0; r < 4; r++) {
          int u = quad * 4 + r;
          int j = nt * 16 + l15;
          float skew = loA[r] ? Bp[nt][r] : Bp[nt + 1][r];
          Pw[u * 72 + j] = (bf16)EXP2F((s[nt][r] + skew) * sc);
        }
    }
    // ---- PV: O += P @ V ; Osum += P @ ones ----
    bf16x8 pa0 = *(const bf16x8*)&Pw[l15 * 72 + quad * 8];
    bf16x8 pa1 = *(const bf16x8*)&Pw[l15 * 72 + 32 + quad * 8];
    Osum = MFMA16(pa0, ones, Osum);
    Osum = MFMA16(pa1, ones, Osum);
#pragma unroll
    for (int nt = 0; nt < 4; nt++) {
      int row = nt * 16 + l15;
      bf16x8 v0 = *(const bf16x8*)(Vc + ((row << 3) + (quad ^ (row & 7))) * 8);
      bf16x8 v1 = *(const bf16x8*)(Vc + ((row << 3) + ((quad + 4) ^ (row & 7))) * 8);
      O[nt] = MFMA16(pa0, v0, O[nt]);
      O[nt] = MFMA16(pa1, v1, O[nt]);
    }
  }
  // ---- epilogue: O / rowsum, write (B,L,H*DH) bf16 ----
  const int b = bh >> 3, hh = bh & 7;
  float inv[4];
#pragma unroll
  for (int r = 0; r < 4; r++) inv[r] = 1.0f / Osum[r];
  bf16* orow = attn + ((size_t)(b * 2048 + i0)) * 512 + hh * 64;
#pragma unroll
  for (int nt = 0; nt < 4; nt++)
#pragma unroll
    for (int r = 0; r < 4; r++)
      orow[(size_t)(quad * 4 + r) * 512 + nt * 16 + l15] = (bf16)(O[nt][r] * inv[r]);
}

// ---------------------------------------------------------------------------
extern "C" void kernel_launch(void* const* d_in, const int* in_sizes, int n_in,
                              void* d_out, int out_size, void* d_ws, size_t ws_size,
                              hipStream_t stream) {
  const float* Q = (const float*)d_in[0];
  const float* K = (const float*)d_in[1];
  const float* V = (const float*)d_in[2];
  const float* Wq = (const float*)d_in[4];
  const float* bq = (const float*)d_in[5];
  const float* Wk = (const float*)d_in[6];
  const float* bk = (const float*)d_in[7];
  const float* Wv = (const float*)d_in[8];
  const float* bv = (const float*)d_in[9];
  const float* fcw = (const float*)d_in[10];
  const float* fcb = (const float*)d_in[11];
  const float* E = (const float*)d_in[12];

  char* ws = (char*)d_ws;
  bf16* Xq = (bf16*)(ws + 0);
  bf16* Xk = (bf16*)(ws + 8388608);
  bf16* Xv = (bf16*)(ws + 16777216);
  bf16* Wqb = (bf16*)(ws + 25165824);
  bf16* Wkb = (bf16*)(ws + 25690112);
  bf16* Wvb = (bf16*)(ws + 26214400);
  bf16* fcwb = (bf16*)(ws + 26738688);
  bf16* Eb = (bf16*)(ws + 27262976);
  bf16* qbuf = (bf16*)(ws + 27525120);
  bf16* kbuf = (bf16*)(ws + 35913728);
  bf16* vbuf = (bf16*)(ws + 44302336);
  bf16* vTb = Xk;
  bf16* attnb = Xq;

  convert_all<<<13440, 256, 0, stream>>>(
      (const float4*)Q, (const float4*)K, (const float4*)V, (const float4*)Wq,
      (const float4*)Wk, (const float4*)Wv, (const float4*)fcw, (const float4*)E,
      (bf16x4*)Xq, (bf16x4*)Xk, (bf16x4*)Xv, (bf16x4*)Wqb, (bf16x4*)Wkb,
      (bf16x4*)Wvb, (bf16x4*)fcwb, (bf16x4*)Eb);

  proj_gemm<<<dim3(64, 4, 3), 256, 0, stream>>>(Xq, Xk, Xv, Wqb, Wkb, Wvb, bq, bk, bv,
                                                qbuf, kbuf, vbuf);

  transpose_v<<<dim3(32, 32), 256, 0, stream>>>(vbuf, vTb);

  attn_kernel<<<1024, 256, 0, stream>>>(qbuf, kbuf, vTb, Eb, attnb);

  final_gemm<<<dim3(64, 4, 1), 256, 0, stream>>>(attnb, fcwb, fcb, (float*)d_out);
}

// Round 9
// 247.278 us; speedup vs baseline: 1.4239x; 1.0147x over previous
//
#include <hip/hip_runtime.h>
#include <stdint.h>

typedef __bf16 bf16;
typedef float f32x4 __attribute__((ext_vector_type(4)));
typedef bf16 bf16x8 __attribute__((ext_vector_type(8)));
typedef bf16 bf16x4 __attribute__((ext_vector_type(4)));

#define MFMA16(a, b, c) __builtin_amdgcn_mfma_f32_16x16x32_bf16((a), (b), (c), 0, 0, 0)
#define EXP2F(x) __builtin_amdgcn_exp2f(x)

__device__ __forceinline__ void gll16(const void* g, void* l) {
  __builtin_amdgcn_global_load_lds((const __attribute__((address_space(1))) void*)g,
                                   (__attribute__((address_space(3))) void*)l, 16, 0, 0);
}

// ---------------------------------------------------------------------------
// fp32 -> bf16 conversion of all tensors, one launch.
// ---------------------------------------------------------------------------
__global__ __launch_bounds__(256) void convert_all(
    const float4* __restrict__ Q, const float4* __restrict__ K, const float4* __restrict__ V,
    const float4* __restrict__ Wq, const float4* __restrict__ Wk, const float4* __restrict__ Wv,
    const float4* __restrict__ fcw, const float4* __restrict__ E,
    bf16x4* __restrict__ Xq, bf16x4* __restrict__ Xk, bf16x4* __restrict__ Xv,
    bf16x4* __restrict__ Wqb, bf16x4* __restrict__ Wkb, bf16x4* __restrict__ Wvb,
    bf16x4* __restrict__ fcb, bf16x4* __restrict__ Eb) {
  int i = blockIdx.x * 256 + threadIdx.x;
  const float4* s;
  bf16x4* d;
  int off;
  if (i < 1048576) { s = Q; d = Xq; off = i; }
  else if (i < 2097152) { s = K; d = Xk; off = i - 1048576; }
  else if (i < 3145728) { s = V; d = Xv; off = i - 2097152; }
  else if (i < 3211264) { s = Wq; d = Wqb; off = i - 3145728; }
  else if (i < 3276800) { s = Wk; d = Wkb; off = i - 3211264; }
  else if (i < 3342336) { s = Wv; d = Wvb; off = i - 3276800; }
  else if (i < 3407872) { s = fcw; d = fcb; off = i - 3342336; }
  else { s = E; d = Eb; off = i - 3407872; }
  float4 v = s[off];
  bf16x4 o;
  o[0] = (bf16)v.x; o[1] = (bf16)v.y; o[2] = (bf16)v.z; o[3] = (bf16)v.w;
  d[off] = o;
}

// ---------------------------------------------------------------------------
// GEMM core: C[128x128] = A[128x512] * Bt[128x512]^T (row-major bf16).
// ---------------------------------------------------------------------------
__device__ __forceinline__ void gemm_core(const bf16* __restrict__ A, const bf16* __restrict__ Bt,
                                          bf16* ldsA, bf16* ldsB, int m0, int n0,
                                          f32x4 acc[4][4]) {
  const int t = threadIdx.x;
  const int lane = t & 63, w = t >> 6;
  const int l15 = lane & 15, quad = lane >> 4;
  const int wm = w >> 1, wn = w & 1;
#pragma unroll
  for (int i = 0; i < 4; i++)
#pragma unroll
    for (int j = 0; j < 4; j++) acc[i][j] = (f32x4){0.f, 0.f, 0.f, 0.f};

  const int ch0 = t, ch1 = t + 256;
  const int r0 = ch0 >> 2, c0 = (ch0 & 3) ^ (r0 & 3);
  const int r1 = ch1 >> 2, c1 = (ch1 & 3) ^ (r1 & 3);

  int aoff[4], boff[4];
#pragma unroll
  for (int mt = 0; mt < 4; mt++) {
    int m = wm * 64 + mt * 16 + l15;
    aoff[mt] = (m << 6) + ((quad ^ (l15 & 3)) << 4);
    int n = wn * 64 + mt * 16 + l15;
    boff[mt] = (n << 6) + ((quad ^ (l15 & 3)) << 4);
  }
  bf16* ldsA1 = ldsA + w * 512;
  bf16* ldsA2 = ldsA + 2048 + w * 512;
  bf16* ldsB1 = ldsB + w * 512;
  bf16* ldsB2 = ldsB + 2048 + w * 512;

  for (int kt = 0; kt < 512; kt += 32) {
    gll16(A + (size_t)(m0 + r0) * 512 + kt + c0 * 8, ldsA1);
    gll16(A + (size_t)(m0 + r1) * 512 + kt + c1 * 8, ldsA2);
    gll16(Bt + (size_t)(n0 + r0) * 512 + kt + c0 * 8, ldsB1);
    gll16(Bt + (size_t)(n0 + r1) * 512 + kt + c1 * 8, ldsB2);
    __syncthreads();
    bf16x8 af[4], bfr[4];
#pragma unroll
    for (int mt = 0; mt < 4; mt++) af[mt] = *(const bf16x8*)((const char*)ldsA + aoff[mt]);
#pragma unroll
    for (int nt = 0; nt < 4; nt++) bfr[nt] = *(const bf16x8*)((const char*)ldsB + boff[nt]);
#pragma unroll
    for (int mt = 0; mt < 4; mt++)
#pragma unroll
      for (int nt = 0; nt < 4; nt++)
        acc[mt][nt] = MFMA16(af[mt], bfr[nt], acc[mt][nt]);
    __syncthreads();
  }
}

__global__ __launch_bounds__(256) void proj_gemm(
    const bf16* __restrict__ Xq, const bf16* __restrict__ Xk, const bf16* __restrict__ Xv,
    const bf16* __restrict__ Wq, const bf16* __restrict__ Wk, const bf16* __restrict__ Wv,
    const float* __restrict__ bq, const float* __restrict__ bk, const float* __restrict__ bv,
    bf16* __restrict__ qb, bf16* __restrict__ kb, bf16* __restrict__ vb) {
  __shared__ bf16 ldsA[128 * 32];
  __shared__ bf16 ldsB[128 * 32];
  const int z = blockIdx.z;
  const bf16* A = z == 0 ? Xq : (z == 1 ? Xk : Xv);
  const bf16* W = z == 0 ? Wq : (z == 1 ? Wk : Wv);
  const float* bias = z == 0 ? bq : (z == 1 ? bk : bv);
  bf16* out = z == 0 ? qb : (z == 1 ? kb : vb);
  const int m0 = blockIdx.x * 128, n0 = blockIdx.y * 128;
  f32x4 acc[4][4];
  gemm_core(A, W, ldsA, ldsB, m0, n0, acc);

  const int t = threadIdx.x;
  const int lane = t & 63, w = t >> 6;
  const int l15 = lane & 15, quad = lane >> 4;
  const int wm = w >> 1, wn = w & 1;
#pragma unroll
  for (int mt = 0; mt < 4; mt++)
#pragma unroll
    for (int nt = 0; nt < 4; nt++)
#pragma unroll
      for (int r = 0; r < 4; r++) {
        int gm = m0 + wm * 64 + mt * 16 + quad * 4 + r;
        int gn = n0 + wn * 64 + nt * 16 + l15;
        float v = acc[mt][nt][r] + bias[gn];
        int b = gm >> 11, l = gm & 2047, h = gn >> 6, d = gn & 63;
        out[(((size_t)(b * 8 + h)) * 2048 + l) * 64 + d] = (bf16)v;
      }
}

__global__ __launch_bounds__(256) void final_gemm(const bf16* __restrict__ A,
                                                  const bf16* __restrict__ W,
                                                  const float* __restrict__ bias,
                                                  float* __restrict__ out) {
  __shared__ bf16 ldsA[128 * 32];
  __shared__ bf16 ldsB[128 * 32];
  const int m0 = blockIdx.x * 128, n0 = blockIdx.y * 128;
  f32x4 acc[4][4];
  gemm_core(A, W, ldsA, ldsB, m0, n0, acc);

  const int t = threadIdx.x;
  const int lane = t & 63, w = t >> 6;
  const int l15 = lane & 15, quad = lane >> 4;
  const int wm = w >> 1, wn = w & 1;
#pragma unroll
  for (int mt = 0; mt < 4; mt++)
#pragma unroll
    for (int nt = 0; nt < 4; nt++)
#pragma unroll
      for (int r = 0; r < 4; r++) {
        int gm = m0 + wm * 64 + mt * 16 + quad * 4 + r;
        int gn = n0 + wn * 64 + nt * 16 + l15;
        out[(size_t)gm * 512 + gn] = acc[mt][nt][r] + bias[gn];
      }
}

// v (B,H,L,64) -> vT (B,H,64,L)
__global__ __launch_bounds__(256) void transpose_v(const bf16* __restrict__ vbuf,
                                                   bf16* __restrict__ vT) {
  __shared__ bf16 tile[64][72];
  const int bh = blockIdx.y, l0 = blockIdx.x * 64;
  const bf16* src = vbuf + ((size_t)bh * 2048 + l0) * 64;
  bf16* dst = vT + (size_t)bh * 64 * 2048 + l0;
  const int t = threadIdx.x;
#pragma unroll
  for (int p = 0; p < 2; p++) {
    int ch = t + p * 256;
    int r = ch >> 3, c8 = ch & 7;
    *(bf16x8*)&tile[r][c8 * 8] = *(const bf16x8*)&src[(size_t)r * 64 + c8 * 8];
  }
  __syncthreads();
#pragma unroll
  for (int p = 0; p < 2; p++) {
    int ch = t + p * 256;
    int dr = ch >> 3, lc = ch & 7;
    bf16x8 v;
#pragma unroll
    for (int j = 0; j < 8; j++) v[j] = tile[lc * 8 + j][dr];
    *(bf16x8*)&dst[(size_t)dr * 2048 + lc * 8] = v;
  }
}

// ---------------------------------------------------------------------------
// Flash attention + relative position, causal. Max-free unnormalized softmax
// => partial sums over j are purely ADDITIVE, so long strips are split into
// j-chunks merged by a cheap normalize kernel (no atomics, no max-merge).
// Jobs (48 per bh, grid 1536, all <=16 tiles, LPT order):
//   job 0..15 : strip 16+j, jt [0,16)      (no diagonal)   -> slot0
//   job 16+2i : strip 15-i, jt [0,16-i)    (full strip)    -> slot0
//   job 17+2i : strip 31-i, jt [16,32-i)   (diag chunk)    -> slot1
// Rows >=1024 are exactly the two-chunk rows -> slot1 fully written, no memset.
// Inner loop = R7 structure: single 16KB K/V LDS buffer, 2 barriers/tile,
// E-band MFMA between staging-issue and consuming barrier, skew via
// ds_bpermute crossbar, P via LDS round-trip, Osum via ones-MFMA.
// 25.6 KB LDS + ~70 VGPR -> up to 6 blocks/CU resident.
// ---------------------------------------------------------------------------
__global__ __launch_bounds__(256, 4) void attn_kernel(
    const bf16* __restrict__ qbuf, const bf16* __restrict__ kbuf,
    const bf16* __restrict__ vT, const bf16* __restrict__ Eb,
    bf16* __restrict__ attnb, bf16* __restrict__ Of1,
    float* __restrict__ Os0, float* __restrict__ Os1) {
  __shared__ bf16 Kl[64 * 64];
  __shared__ bf16 Vl[64 * 64];
  __shared__ bf16 Pl[4][16 * 72];
  const int t = threadIdx.x, w = t >> 6, lane = t & 63;
  const int l15 = lane & 15, quad = lane >> 4;
  const int x = blockIdx.x;
  const int bh = x & 31, job = x >> 5;
  int strip, jt0, jt1;
  bool isB;
  if (job < 16) {
    strip = 16 + job; jt0 = 0; jt1 = 16; isB = false;
  } else {
    int k = job - 16, i = k >> 1;
    if ((k & 1) == 0) { strip = 15 - i; jt0 = 0; jt1 = 16 - i; isB = false; }
    else { strip = 31 - i; jt0 = 16; jt1 = 32 - i; isB = true; }
  }
  const int i0 = strip * 64 + w * 16;  // this wave's 16 q-rows
  bf16* Pw = Pl[w];
  const bf16* qh = qbuf + (size_t)bh * 2048 * 64;
  const bf16* kh = kbuf + (size_t)bh * 2048 * 64;
  const bf16* vh = vT + (size_t)bh * 64 * 2048;

  // staging: slot s holds (row = s>>3, chunk = (s&7)^(row&7)); thread t does
  // slots t and t+256; wave-uniform LDS byte base + lane*16B.
  const int sr0 = t >> 3, sc0 = (t & 7) ^ (sr0 & 7);
  const int sr1 = sr0 + 32;
  const int wb0 = (t & 192) * 16;  // byte offset of this wave's slot group
  const int wb1 = 4096 + wb0;

  // bpermute lane addresses + tile-select mask, per acc register r
  int bpaddr[4];
  bool loA[4];
#pragma unroll
  for (int r = 0; r < 4; r++) {
    int u = quad * 4 + r;
    bpaddr[r] = (((l15 + 15 - u) & 15) + 16 * quad) * 4;
    loA[r] = (l15 <= u);  // source tile nt (else nt+1)
  }

  bf16x8 aq0, aq1;
  {
    const bf16* qrow = qh + (size_t)(i0 + l15) * 64 + quad * 8;
    aq0 = *(const bf16x8*)qrow;
    aq1 = *(const bf16x8*)(qrow + 32);
  }
  bf16x8 ones;
#pragma unroll
  for (int j = 0; j < 8; j++) ones[j] = (bf16)1.0f;

  f32x4 O[4], Osum;
  Osum = (f32x4){0.f, 0.f, 0.f, 0.f};
#pragma unroll
  for (int i = 0; i < 4; i++) O[i] = (f32x4){0.f, 0.f, 0.f, 0.f};
  const float sc = 0.125f * 1.44269504088896f;  // 1/sqrt(64) * log2(e)
  const int ebase00 = 2047 - i0 - 15;

  // ---- carry init: T-tile c-range [0,16) of the first chunk tile ----
  float Bpc[4];
  {
    int er = ebase00 + jt0 * 64 + l15;
    er = er > 2047 ? 2047 : er;
    const bf16* erow = Eb + (size_t)er * 64 + quad * 8;
    bf16x8 e0 = *(const bf16x8*)erow;
    bf16x8 e1 = *(const bf16x8*)(erow + 32);
    f32x4 zz = (f32x4){0.f, 0.f, 0.f, 0.f};
    zz = MFMA16(aq0, e0, zz);
    zz = MFMA16(aq1, e1, zz);
#pragma unroll
    for (int r = 0; r < 4; r++)
      Bpc[r] = __int_as_float(__builtin_amdgcn_ds_bpermute(bpaddr[r], __float_as_int(zz[r])));
  }

  for (int jt = jt0; jt < jt1; jt++) {
    const int j0 = jt * 64;
    const bool diag = (jt == strip);  // only the last tile of A/B chunks
    __syncthreads();  // all waves done reading K/V of previous tile
    // ---- issue staging for this tile (async into LDS) ----
    gll16(kh + (size_t)(j0 + sr0) * 64 + sc0 * 8, (char*)Kl + wb0);
    gll16(kh + (size_t)(j0 + sr1) * 64 + sc0 * 8, (char*)Kl + wb1);
    gll16(vh + (size_t)sr0 * 2048 + j0 + sc0 * 8, (char*)Vl + wb0);
    gll16(vh + (size_t)sr1 * 2048 + j0 + sc0 * 8, (char*)Vl + wb1);
    // ---- E-band: fresh T-tiles nt=1..4 (nt=0 carried); overlaps staging ----
    float Bp[5][4];
#pragma unroll
    for (int r = 0; r < 4; r++) Bp[0][r] = Bpc[r];
    const int ebase = ebase00 + j0;
#pragma unroll
    for (int nt = 1; nt < 5; nt++) {
      int er = ebase + nt * 16 + l15;
      er = er > 2047 ? 2047 : er;  // clamped rows feed only masked entries
      const bf16* erow = Eb + (size_t)er * 64 + quad * 8;
      bf16x8 e0 = *(const bf16x8*)erow;
      bf16x8 e1 = *(const bf16x8*)(erow + 32);
      f32x4 zz = (f32x4){0.f, 0.f, 0.f, 0.f};
      zz = MFMA16(aq0, e0, zz);
      zz = MFMA16(aq1, e1, zz);
#pragma unroll
      for (int r = 0; r < 4; r++)
        Bp[nt][r] =
            __int_as_float(__builtin_amdgcn_ds_bpermute(bpaddr[r], __float_as_int(zz[r])));
    }
#pragma unroll
    for (int r = 0; r < 4; r++) Bpc[r] = Bp[4][r];

    __syncthreads();  // staging complete (vmcnt drained before barrier)
    // ---- S = q @ k^T from LDS (swizzled b128 reads) ----
    f32x4 s[4];
#pragma unroll
    for (int nt = 0; nt < 4; nt++) {
      int row = nt * 16 + l15;
      bf16x8 k0 = *(const bf16x8*)(Kl + ((row << 3) + (quad ^ (row & 7))) * 8);
      bf16x8 k1 = *(const bf16x8*)(Kl + ((row << 3) + ((quad + 4) ^ (row & 7))) * 8);
      f32x4 zz = (f32x4){0.f, 0.f, 0.f, 0.f};
      zz = MFMA16(aq0, k0, zz);
      s[nt] = MFMA16(aq1, k1, zz);
    }
    // ---- logits: skew add + scale (+ mask on diag tile) + exp2 + P ----
    if (diag) {
#pragma unroll
      for (int nt = 0; nt < 4; nt++)
#pragma unroll
        for (int r = 0; r < 4; r++) {
          int u = quad * 4 + r;
          int j = nt * 16 + l15;
          float skew = loA[r] ? Bp[nt][r] : Bp[nt + 1][r];
          float logit = (s[nt][r] + skew) * sc;
          if (j0 + j > i0 + u) logit = -1e30f;  // causal; exp2 -> 0
          Pw[u * 72 + j] = (bf16)EXP2F(logit);
        }
    } else {
#pragma unroll
      for (int nt = 0; nt < 4; nt++)
#pragma unroll
        for (int r = 0; r < 4; r++) {
          int u = quad * 4 + r;
          int j = nt * 16 + l15;
          float skew = loA[r] ? Bp[nt][r] : Bp[nt + 1][r];
          Pw[u * 72 + j] = (bf16)EXP2F((s[nt][r] + skew) * sc);
        }
    }
    // ---- PV: O += P @ V ; Osum += P @ ones ----
    bf16x8 pa0 = *(const bf16x8*)&Pw[l15 * 72 + quad * 8];
    bf16x8 pa1 = *(const bf16x8*)&Pw[l15 * 72 + 32 + quad * 8];
    Osum = MFMA16(pa0, ones, Osum);
    Osum = MFMA16(pa1, ones, Osum);
#pragma unroll
    for (int nt = 0; nt < 4; nt++) {
      int row = nt * 16 + l15;
      bf16x8 v0 = *(const bf16x8*)(Vl + ((row << 3) + (quad ^ (row & 7))) * 8);
      bf16x8 v1 = *(const bf16x8*)(Vl + ((row << 3) + ((quad + 4) ^ (row & 7))) * 8);
      O[nt] = MFMA16(pa0, v0, O[nt]);
      O[nt] = MFMA16(pa1, v1, O[nt]);
    }
  }
  // ---- epilogue: UNNORMALIZED partial O (bf16) + rowsum (f32) ----
  if (isB) {
    bf16* orow = Of1 + ((size_t)(bh * 1024 + (i0 - 1024))) * 64;
#pragma unroll
    for (int nt = 0; nt < 4; nt++)
#pragma unroll
      for (int r = 0; r < 4; r++)
        orow[(size_t)(quad * 4 + r) * 64 + nt * 16 + l15] = (bf16)O[nt][r];
    if (l15 == 0) {
#pragma unroll
      for (int r = 0; r < 4; r++) Os1[bh * 1024 + (i0 - 1024) + quad * 4 + r] = Osum[r];
    }
  } else {
    const int b = bh >> 3, hh = bh & 7;
    bf16* orow = attnb + ((size_t)(b * 2048 + i0)) * 512 + hh * 64;
#pragma unroll
    for (int nt = 0; nt < 4; nt++)
#pragma unroll
      for (int r = 0; r < 4; r++)
        orow[(size_t)(quad * 4 + r) * 512 + nt * 16 + l15] = (bf16)O[nt][r];
    if (l15 == 0) {
#pragma unroll
      for (int r = 0; r < 4; r++) Os0[bh * 2048 + i0 + quad * 4 + r] = Osum[r];
    }
  }
}

// ---------------------------------------------------------------------------
// normalize: attnb = (slot0 + slot1?) / (s0 + s1?), in place. vec8 per thread.
// ---------------------------------------------------------------------------
__global__ __launch_bounds__(256) void norm_kernel(bf16x8* __restrict__ attnb,
                                                   const bf16x8* __restrict__ Of1,
                                                   const float* __restrict__ Os0,
                                                   const float* __restrict__ Os1) {
  int i = blockIdx.x * 256 + threadIdx.x;  // vec8 index, 524288 total
  int col8 = i & 63;                       // 64 vec8 per row of 512
  int row = i >> 6;                        // b*2048 + l
  int b = row >> 11, l = row & 2047, h = col8 >> 3;
  int bh = b * 8 + h;
  float s = Os0[bh * 2048 + l];
  bf16x8 v0 = attnb[i];
  float acc[8];
#pragma unroll
  for (int j = 0; j < 8; j++) acc[j] = (float)v0[j];
  if (l >= 1024) {
    s += Os1[bh * 1024 + l - 1024];
    bf16x8 v1 = Of1[(size_t)(bh * 1024 + l - 1024) * 8 + (col8 & 7)];
#pragma unroll
    for (int j = 0; j < 8; j++) acc[j] += (float)v1[j];
  }
  float inv = 1.0f / s;
  bf16x8 o;
#pragma unroll
  for (int j = 0; j < 8; j++) o[j] = (bf16)(acc[j] * inv);
  attnb[i] = o;
}

// ---------------------------------------------------------------------------
extern "C" void kernel_launch(void* const* d_in, const int* in_sizes, int n_in,
                              void* d_out, int out_size, void* d_ws, size_t ws_size,
                              hipStream_t stream) {
  const float* Q = (const float*)d_in[0];
  const float* K = (const float*)d_in[1];
  const float* V = (const float*)d_in[2];
  const float* Wq = (const float*)d_in[4];
  const float* bq = (const float*)d_in[5];
  const float* Wk = (const float*)d_in[6];
  const float* bk = (const float*)d_in[7];
  const float* Wv = (const float*)d_in[8];
  const float* bv = (const float*)d_in[9];
  const float* fcw = (const float*)d_in[10];
  const float* fcb = (const float*)d_in[11];
  const float* E = (const float*)d_in[12];

  char* ws = (char*)d_ws;
  bf16* Xq = (bf16*)(ws + 0);
  bf16* Xk = (bf16*)(ws + 8388608);
  bf16* Xv = (bf16*)(ws + 16777216);
  bf16* Wqb = (bf16*)(ws + 25165824);
  bf16* Wkb = (bf16*)(ws + 25690112);
  bf16* Wvb = (bf16*)(ws + 26214400);
  bf16* fcwb = (bf16*)(ws + 26738688);
  bf16* Eb = (bf16*)(ws + 27262976);
  bf16* qbuf = (bf16*)(ws + 27525120);
  bf16* kbuf = (bf16*)(ws + 35913728);
  bf16* vbuf = (bf16*)(ws + 44302336);
  bf16* Of1 = (bf16*)(ws + 52690944);   // 32*1024*64 bf16 = 4 MiB
  float* Os0 = (float*)(ws + 56885248); // 32*2048 f32 = 256 KiB
  float* Os1 = (float*)(ws + 57147392); // 32*1024 f32 = 128 KiB
  bf16* vTb = Xk;
  bf16* attnb = Xq;

  convert_all<<<13440, 256, 0, stream>>>(
      (const float4*)Q, (const float4*)K, (const float4*)V, (const float4*)Wq,
      (const float4*)Wk, (const float4*)Wv, (const float4*)fcw, (const float4*)E,
      (bf16x4*)Xq, (bf16x4*)Xk, (bf16x4*)Xv, (bf16x4*)Wqb, (bf16x4*)Wkb,
      (bf16x4*)Wvb, (bf16x4*)fcwb, (bf16x4*)Eb);

  proj_gemm<<<dim3(64, 4, 3), 256, 0, stream>>>(Xq, Xk, Xv, Wqb, Wkb, Wvb, bq, bk, bv,
                                                qbuf, kbuf, vbuf);

  transpose_v<<<dim3(32, 32), 256, 0, stream>>>(vbuf, vTb);

  attn_kernel<<<1536, 256, 0, stream>>>(qbuf, kbuf, vTb, Eb, attnb, Of1, Os0, Os1);

  norm_kernel<<<2048, 256, 0, stream>>>((bf16x8*)attnb, (const bf16x8*)Of1, Os0, Os1);

  final_gemm<<<dim3(64, 4, 1), 256, 0, stream>>>(attnb, fcwb, fcb, (float*)d_out);
}